// Round 6
// baseline (272.853 us; speedup 1.0000x reference)
//
#include <hip/hip_runtime.h>
#include <hip/hip_cooperative_groups.h>
#include <math.h>

// Problem constants (from reference)
#define Bn   16
#define Cn   64
#define Nn   65536        // H*W = 256*256
#define Sn   32           // n-slices per batch (one slice per block)
#define Ln   (Nn / Sn)    // 2048 k-elements per slice (512 per wave)
#define REDn 16
#define GRID (Bn * Sn)    // 512 blocks

typedef float    f32x4  __attribute__((ext_vector_type(4)));
typedef float    f32x16 __attribute__((ext_vector_type(16)));
typedef __fp16   fp16x2 __attribute__((ext_vector_type(2)));
typedef _Float16 f16x8  __attribute__((ext_vector_type(8)));

union half8_u {
  f16x8  v;
  fp16x2 h[4];
};

// ---------------------------------------------------------------------------
// Fused cooperative kernel:
//  phase 1: per-block gram+pool partials for its (b,s) slice  -> d_out front
//  sync
//  phase 2: blocks 0..15 reduce partials + tiny MLP -> gate g -> d_ws
//  sync
//  phase 3: grid-stride out = x * g  (x re-read should hit L3)
// ---------------------------------------------------------------------------
__global__ __launch_bounds__(256, 2) void fused_kernel(
    const float* __restrict__ x, const float* __restrict__ Wrow,
    const float* __restrict__ brow,
    const float* __restrict__ W1, const float* __restrict__ b1,
    const float* __restrict__ W2, const float* __restrict__ b2,
    float* __restrict__ out, float* __restrict__ ws) {
  cooperative_groups::grid_group grid = cooperative_groups::this_grid();

  const int bid  = blockIdx.x;
  const int b    = bid >> 5;        // batch
  const int s    = bid & 31;        // slice
  const int tid  = threadIdx.x;
  const int wid  = tid >> 6;
  const int lane = tid & 63;
  const int l31  = lane & 31;
  const int lhi  = lane >> 5;
  const int rr   = lane >> 2;       // staging row-within-group (0..15)
  const int cc   = lane & 3;        // staging 16B chunk (0..3)

  const float* xb = x + (size_t)b * Cn * Nn;

  __shared__ float stage[4][Cn * 17];   // per-wave [64 rows][17] f32 (pad)
  __shared__ float corr_s[Cn][Cn + 1];
  __shared__ float pool_lds0[4][32];
  __shared__ float pool_lds1[4][32];
  __shared__ float rs_s[4][Cn], rp_s[4][Cn];   // phase-2 reduction
  __shared__ float y_s[Cn];
  __shared__ float z_s[REDn];

  // ======================= phase 1: gram + pool ============================
  {
    float* wb = &stage[wid][0];

    // staging: instruction i covers rows 16i..16i+15, 4 lanes/row, 64B/row
    const float* gsrc[4];
    int widx[4];
#pragma unroll
    for (int i = 0; i < 4; ++i) {
      const int row = 16 * i + rr;
      gsrc[i] = xb + (size_t)row * Nn + cc * 4;
      widx[i] = row * 17 + cc * 4;
    }
    // fragment read indices (conflict-free via pad 17)
    const int fA = l31 * 17 + lhi * 8;          // rows 0..31
    const int fB = (l31 + 32) * 17 + lhi * 8;   // rows 32..63

    const int kw = s * Ln + wid * (Ln / 4);     // wave's k base; 32 tiles of 16

    f32x16 acc00, acc01, acc11;
#pragma unroll
    for (int r = 0; r < 16; ++r) { acc00[r] = 0.f; acc01[r] = 0.f; acc11[r] = 0.f; }
    float pool0 = 0.f, pool1 = 0.f;

    // register prefetch pipeline, 2 tiles deep
    f32x4 sA[4], sB[4];
#pragma unroll
    for (int i = 0; i < 4; ++i) sA[i] = *(const f32x4*)(gsrc[i] + kw);
#pragma unroll
    for (int i = 0; i < 4; ++i) sB[i] = *(const f32x4*)(gsrc[i] + kw + 16);

    auto step = [&](f32x4* stg, int t) {
#pragma unroll
      for (int i = 0; i < 4; ++i) *(f32x4*)&wb[widx[i]] = stg[i];
      if (t < 30) {
        const int ko = kw + (t + 2) * 16;
#pragma unroll
        for (int i = 0; i < 4; ++i) stg[i] = *(const f32x4*)(gsrc[i] + ko);
      }
      f32x4 a0 = *(const f32x4*)&wb[fA];
      f32x4 a1 = *(const f32x4*)&wb[fA + 4];
      f32x4 c0 = *(const f32x4*)&wb[fB];
      f32x4 c1 = *(const f32x4*)&wb[fB + 4];

      pool0 += (a0[0] + a0[1]) + (a0[2] + a0[3]) + (a1[0] + a1[1]) + (a1[2] + a1[3]);
      pool1 += (c0[0] + c0[1]) + (c0[2] + c0[3]) + (c1[0] + c1[1]) + (c1[2] + c1[3]);

      half8_u au, bu;
      au.h[0] = __builtin_amdgcn_cvt_pkrtz(a0[0], a0[1]);
      au.h[1] = __builtin_amdgcn_cvt_pkrtz(a0[2], a0[3]);
      au.h[2] = __builtin_amdgcn_cvt_pkrtz(a1[0], a1[1]);
      au.h[3] = __builtin_amdgcn_cvt_pkrtz(a1[2], a1[3]);
      bu.h[0] = __builtin_amdgcn_cvt_pkrtz(c0[0], c0[1]);
      bu.h[1] = __builtin_amdgcn_cvt_pkrtz(c0[2], c0[3]);
      bu.h[2] = __builtin_amdgcn_cvt_pkrtz(c1[0], c1[1]);
      bu.h[3] = __builtin_amdgcn_cvt_pkrtz(c1[2], c1[3]);

      acc00 = __builtin_amdgcn_mfma_f32_32x32x16_f16(au.v, au.v, acc00, 0, 0, 0);
      acc01 = __builtin_amdgcn_mfma_f32_32x32x16_f16(au.v, bu.v, acc01, 0, 0, 0);
      acc11 = __builtin_amdgcn_mfma_f32_32x32x16_f16(bu.v, bu.v, acc11, 0, 0, 0);
    };

#pragma unroll
    for (int tp = 0; tp < 16; ++tp) {
      step(sA, 2 * tp);
      step(sB, 2 * tp + 1);
    }

    pool0 += __shfl_down(pool0, 32);
    pool1 += __shfl_down(pool1, 32);
    if (lane < 32) {
      pool_lds0[wid][lane] = pool0;
      pool_lds1[wid][lane] = pool1;
    }

    // sequential wave accumulation of the 64x64 corr tile
    for (int w = 0; w < 4; ++w) {
      __syncthreads();
      if (wid == w) {
#pragma unroll
        for (int r = 0; r < 16; ++r) {
          // verified C/D layout (32x32 MFMA): col=lane&31, row=(r&3)+8*(r>>2)+4*(lane>>5)
          const int i = (r & 3) + 8 * (r >> 2) + 4 * lhi;
          const int j = l31;
          if (w == 0) {
            corr_s[i][j]           = acc00[r];
            corr_s[i][j + 32]      = acc01[r];
            corr_s[j + 32][i]      = acc01[r];   // symmetric mirror
            corr_s[i + 32][j + 32] = acc11[r];
          } else {
            corr_s[i][j]           += acc00[r];
            corr_s[i][j + 32]      += acc01[r];
            corr_s[j + 32][i]      += acc01[r];
            corr_s[i + 32][j + 32] += acc11[r];
          }
        }
      }
    }
    __syncthreads();

    if (tid < Cn) {
      const float* wr = Wrow + tid * Cn;
      float so = 0.f;
#pragma unroll 8
      for (int d = 0; d < Cn; ++d) so += corr_s[tid][d] * wr[d];
      float pp = 0.f;
      if (tid < 32) {
#pragma unroll
        for (int w = 0; w < 4; ++w) pp += pool_lds0[w][tid];
      } else {
#pragma unroll
        for (int w = 0; w < 4; ++w) pp += pool_lds1[w][tid - 32];
      }
      float* o = out + (size_t)bid * (2 * Cn);   // partials in front of d_out
      o[tid]      = so;
      o[Cn + tid] = pp;
    }
  }

  grid.sync();

  // ======================= phase 2: gate g (blocks 0..15) ==================
  if (bid < Bn) {
    const int c = tid & 63;
    const int q = tid >> 6;
    float so = 0.f, pl = 0.f;
    for (int ss = q * 8; ss < q * 8 + 8; ++ss) {
      const float* p = out + (size_t)(bid * Sn + ss) * (2 * Cn);
      so += p[c];
      pl += p[Cn + c];
    }
    rs_s[q][c] = so;
    rp_s[q][c] = pl;
    __syncthreads();
    if (tid < Cn) {
      so = rs_s[0][tid] + rs_s[1][tid] + rs_s[2][tid] + rs_s[3][tid];
      pl = rp_s[0][tid] + rp_s[1][tid] + rp_s[2][tid] + rp_s[3][tid];
      y_s[tid] = (so + pl) * (1.0f / (float)Nn) + brow[tid];
    }
    __syncthreads();
    if (tid < REDn) {
      float z = b1[tid];
#pragma unroll 8
      for (int c2 = 0; c2 < Cn; ++c2) z += W1[tid * Cn + c2] * y_s[c2];
      z_s[tid] = fmaxf(z, 0.f);
    }
    __syncthreads();
    if (tid < Cn) {
      float a = b2[tid];
#pragma unroll
      for (int r = 0; r < REDn; ++r) a += W2[tid * REDn + r] * z_s[r];
      ws[bid * Cn + tid] = 1.0f / (1.0f + expf(-a));   // gate
    }
  }

  grid.sync();

  // ======================= phase 3: out = x * g ============================
  {
    const float* g  = ws;
    const f32x4* xv = (const f32x4*)x;
    f32x4*       ov = (f32x4*)out;
    const size_t stride = (size_t)GRID * 256;          // 131072 threads
    const size_t base   = (size_t)bid * 256 + tid;
    // total float4 = 16777216 = 128 * stride; 2-way unrolled
#pragma unroll 1
    for (int it = 0; it < 64; ++it) {
      const size_t i0 = base + (size_t)(2 * it) * stride;
      const size_t i1 = i0 + stride;
      f32x4 v0 = xv[i0];
      f32x4 v1 = xv[i1];
      const float g0 = g[i0 >> 14];   // 16384 float4 per (b,c)
      const float g1 = g[i1 >> 14];
      v0 *= g0;
      v1 *= g1;
      ov[i0] = v0;
      ov[i1] = v1;
    }
  }
}

// ---------------------------------------------------------------------------
extern "C" void kernel_launch(void* const* d_in, const int* in_sizes, int n_in,
                              void* d_out, int out_size, void* d_ws, size_t ws_size,
                              hipStream_t stream) {
  const float* x    = (const float*)d_in[0];
  const float* Wrow = (const float*)d_in[1];
  const float* brow = (const float*)d_in[2];
  const float* W1   = (const float*)d_in[3];
  const float* b1   = (const float*)d_in[4];
  const float* W2   = (const float*)d_in[5];
  const float* b2   = (const float*)d_in[6];
  float* out = (float*)d_out;
  float* ws  = (float*)d_ws;   // gate g: 16*64 floats = 4 KB

  void* args[] = {(void*)&x, (void*)&Wrow, (void*)&brow, (void*)&W1,
                  (void*)&b1, (void*)&W2, (void*)&b2, (void*)&out, (void*)&ws};
  hipLaunchCooperativeKernel((void*)fused_kernel, dim3(GRID), dim3(256),
                             args, 0, stream);
}